// Round 7
// baseline (538.753 us; speedup 1.0000x reference)
//
#include <hip/hip_runtime.h>
#include <math.h>

#define BB 4
#define CI 6
#define LL 4096
#define DMC 72
#define DIC 144
#define KD 4
#define NS 8
#define RD 4
#define NLAYER 2
#define GRP 12
#define NCH 128   // chunks per scan
#define TS 32     // steps per chunk
#define PP 4356   // padded 66x66 plane
#define L2E 1.4426950408889634f

__device__ __forceinline__ float sigmoidf_(float x){ return 1.f/(1.f+__expf(-x)); }
__device__ __forceinline__ float siluf_(float x){ return x*sigmoidf_(x); }
// fast softplus: |err| << 2e-3 tolerance
__device__ __forceinline__ float softplusf_(float x){
  return fmaxf(x,0.f) + __logf(1.f + __expf(-fabsf(x)));
}

__device__ __forceinline__ int padidx(int p){ return 66*(p>>6) + (p&63) + 67; }

// spatial position p (row-major h*64+w) for scan index l of direction k
__device__ __forceinline__ int dirmap(int k, int l){
  switch(k & 3){
    case 0: return l;
    case 1: return ((l & 63) << 6) | (l >> 6);
    case 2: return (LL-1) - l;
    default: { int m = (LL-1) - l; return ((m & 63) << 6) | (m >> 6); }
  }
}

#define LOAD9(ip, a) do { \
  a[0]=(ip)[-67]; a[1]=(ip)[-66]; a[2]=(ip)[-65]; \
  a[3]=(ip)[-1];  a[4]=(ip)[0];   a[5]=(ip)[1];   \
  a[6]=(ip)[65];  a[7]=(ip)[66];  a[8]=(ip)[67];  } while(0)

// ---------- zero halos of all padded planes ----------
__global__ void k_halo(float* __restrict__ pads, int nplanes){
  int plane = blockIdx.x;
  if (plane >= nplanes) return;
  int t = threadIdx.x;
  if (t >= 260) return;
  float* pl = pads + (size_t)plane*PP;
  int off;
  if (t < 132){
    int row = (t < 66) ? 0 : 65;
    int col = (t < 66) ? t : t-66;
    off = row*66 + col;
  } else {
    int j = t - 132;
    int col = (j < 64) ? 0 : 65;
    int row = 1 + (j & 63);
    off = row*66 + col;
  }
  pl[off] = 0.f;
}

// ---------- pad copy of the input image ----------
__global__ void k_pad_img(const float* __restrict__ img, float* __restrict__ img_pad){
  int idx = blockIdx.x*256 + threadIdx.x;
  if (idx >= BB*CI*LL) return;
  int p = idx & 4095; int bc = idx >> 12;
  img_pad[(size_t)bc*PP + padidx(p)] = img[idx];
}

// ---------- conv 6->72 3x3 + lrelu(0.01); padded in, padded out ----------
__global__ void k_conv1(const float* __restrict__ img_pad, const float* __restrict__ w,
                        const float* __restrict__ bias, float* __restrict__ tmp_pad){
  int bid = blockIdx.x;
  int t = bid & 15; int r = bid >> 4; int o = r % DMC; int b = r / DMC;
  int p = t*256 + threadIdx.x;
  int pb = padidx(p);
  float acc = bias[o];
  const float* wb = w + o*CI*9;
  #pragma unroll
  for (int ic=0; ic<CI; ++ic){
    const float* ip = img_pad + (size_t)(b*CI+ic)*PP + pb;
    float a[9]; LOAD9(ip, a);
    #pragma unroll
    for (int q=0;q<9;++q) acc += a[q]*wb[ic*9+q];
  }
  tmp_pad[(size_t)(b*DMC+o)*PP + pb] = acc >= 0.f ? acc : 0.01f*acc;
}

// ---------- conv2 init: bias + 1x1 shortcut -> x (pre-lrelu) ----------
__global__ void k_conv2init(const float* __restrict__ img, const float* __restrict__ b2,
                            const float* __restrict__ wsc, const float* __restrict__ bsc,
                            float* __restrict__ xout){
  int bid = blockIdx.x;
  int t = bid & 15; int r = bid >> 4; int og = r % 18; int b = r / 18;
  int p = t*256 + threadIdx.x;
  float acc[4];
  #pragma unroll
  for (int j=0;j<4;++j) acc[j] = b2[og*4+j] + bsc[og*4+j];
  #pragma unroll
  for (int ic=0; ic<CI; ++ic){
    float v = img[((b*CI+ic)<<12)+p];
    #pragma unroll
    for (int j=0;j<4;++j) acc[j] += v * wsc[(og*4+j)*CI+ic];
  }
  #pragma unroll
  for (int j=0;j<4;++j)
    xout[((b*DMC+og*4+j)<<12)+p] = acc[j];
}

// ---------- conv 72->72 3x3 partials, ic-split x2, atomic accumulate (no lrelu) ----------
__global__ void k_conv2(const float* __restrict__ tmp_pad,
                        const float* __restrict__ w2, float* __restrict__ xout){
  int bid = blockIdx.x;
  int t = bid & 15; int r = bid >> 4; int og = r % 18; r /= 18;
  int icg = r & 1; int b = r >> 1;
  int p = t*256 + threadIdx.x;
  int pb = padidx(p);
  float acc[4] = {0.f,0.f,0.f,0.f};
  const float* ipb = tmp_pad + (size_t)b*DMC*PP + pb;
  const float* wb  = w2 + (size_t)(og*4)*DMC*9;
  #pragma unroll 2
  for (int ii=0; ii<36; ++ii){
    int ic = icg*36 + ii;
    const float* ip = ipb + (size_t)ic*PP;
    float a[9]; LOAD9(ip, a);
    const float* wp = wb + ic*9;
    #pragma unroll
    for (int j=0;j<4;++j){
      float s = 0.f;
      #pragma unroll
      for (int q=0;q<9;++q) s += a[q]*wp[(size_t)j*DMC*9 + q];
      acc[j] += s;
    }
  }
  #pragma unroll
  for (int j=0;j<4;++j)
    atomicAdd(xout + ((b*DMC+og*4+j)<<12)+p, acc[j]);
}

// ---------- xz (optional lrelu on load): 144 ch -> padded planes; z -> z_t [b][p][c] ----------
__global__ void k_xz(const float* __restrict__ x, const float* __restrict__ inw,
                     float* __restrict__ xz_pad, float* __restrict__ z_t, int relu){
  int bid = blockIdx.x;
  int t = bid & 15; int r = bid >> 4; int eg = r % 36; int b = r / 36;
  int p = t*256 + threadIdx.x;
  float acc[8] = {0.f,0.f,0.f,0.f,0.f,0.f,0.f,0.f};
  for (int c0=0; c0<DMC; c0+=4){
    float a[4];
    #pragma unroll
    for (int q=0;q<4;++q) a[q] = x[((b*DMC+c0+q)<<12)+p];
    if (relu){
      #pragma unroll
      for (int q=0;q<4;++q) a[q] = a[q] >= 0.f ? a[q] : 0.01f*a[q];
    }
    #pragma unroll
    for (int j=0;j<8;++j){
      float4 w = *(const float4*)(inw + (eg*8+j)*DMC + c0);
      acc[j] += a[0]*w.x + a[1]*w.y + a[2]*w.z + a[3]*w.w;
    }
  }
  if (eg < 18){
    int pb = padidx(p);
    #pragma unroll
    for (int j=0;j<8;++j) xz_pad[(size_t)(b*DIC+eg*8+j)*PP + pb] = acc[j];
  } else {
    float* zb = z_t + ((size_t)b*LL+p)*DIC + (eg*8-DIC);
    *(float4*)(zb)   = make_float4(acc[0],acc[1],acc[2],acc[3]);
    *(float4*)(zb+4) = make_float4(acc[4],acc[5],acc[6],acc[7]);
  }
}

// ---------- depthwise 3x3 + bias + silu -> xi_t [b][p][c] ----------
__global__ void k_dw(const float* __restrict__ xz_pad, const float* __restrict__ dww,
                     const float* __restrict__ dwb, float* __restrict__ xi_t){
  int bid = blockIdx.x;
  int t = bid & 15; int r = bid >> 4; int c = r % DIC; int b = r / DIC;
  int p = t*256 + threadIdx.x;
  int pb = padidx(p);
  const float* ip = xz_pad + (size_t)(b*DIC+c)*PP + pb;
  const float* wp = dww + c*9;
  float a[9]; LOAD9(ip, a);
  float acc = dwb[c];
  #pragma unroll
  for (int q=0;q<9;++q) acc += a[q]*wp[q];
  xi_t[((size_t)b*LL+p)*DIC + c] = siluf_(acc);
}

// ---------- x_dbl [bk][p][20]; 10 ch-groups of 2; thread=(b,part,k,ptile) ----------
__global__ void k_xdbl(const float* __restrict__ xi_t, const float* __restrict__ xpw,
                       float* __restrict__ xdbl){
  int bid = blockIdx.x;
  int t = bid & 15; int r = bid >> 4;
  int kk = r & 3; r >>= 2; int part = r % 10; int b = r / 10;
  int p = t*256 + threadIdx.x;
  const float* xib = xi_t + ((size_t)b*LL + p)*DIC;
  const float* wk = xpw + (size_t)(kk*20 + part*2)*DIC;
  float acc[2] = {0.f,0.f};
  for (int d=0; d<DIC; d+=4){
    float4 v = *(const float4*)(xib + d);
    #pragma unroll
    for (int c=0;c<2;++c){
      float4 w = *(const float4*)(wk + (size_t)c*DIC + d);
      acc[c] += v.x*w.x + v.y*w.y + v.z*w.z + v.w*w.w;
    }
  }
  float* dst = xdbl + ((size_t)(b*KD+kk)*LL + p)*20 + part*2;
  dst[0] = acc[0]; dst[1] = acc[1];
}

__device__ __forceinline__ void scan_decode(int idx, int& b, int& k, int& ch, int& c){
  c = idx % DIC;
  int r = idx / DIC;
  ch = r % NCH;
  r /= NCH;
  k = r & 3; b = r >> 2;
}

// ---------- P1: per-chunk summaries (cumA, partial state), layout [bk][ch][n][c] ----------
__global__ void k_p1(const float* __restrict__ xi_t, const float* __restrict__ xdbl,
                     const float* __restrict__ dtpw, const float* __restrict__ dtpb,
                     const float* __restrict__ alog,
                     float* __restrict__ cumA, float* __restrict__ hp){
  int idx = blockIdx.x*256 + threadIdx.x;
  if (idx >= BB*KD*NCH*DIC) return;
  int b,k,ch,c; scan_decode(idx,b,k,ch,c);
  float Arow[NS];   // pre-scaled by log2(e): exp(dt*A) = exp2(dt*Arow)
  #pragma unroll
  for (int n=0;n<NS;++n) Arow[n] = -__expf(alog[(k*DIC+c)*NS+n]) * L2E;
  float4 wdt = *(const float4*)(dtpw + (k*DIC+c)*RD);
  float bdt = dtpb[k*DIC+c];
  const float* xd = xdbl + (size_t)(b*KD+k)*LL*20;
  const float* xib = xi_t + (size_t)b*LL*DIC + c;
  float h[NS];
  #pragma unroll
  for (int n=0;n<NS;++n) h[n]=0.f;
  float sumd = 0.f;
  #pragma unroll 2
  for (int t=0; t<TS; ++t){
    int l = ch*TS + t;
    int ps = dirmap(k,l);
    const float* row = xd + (size_t)ps*20;
    float4 q0 = *(const float4*)(row);
    float4 q1 = *(const float4*)(row+4);
    float4 q2 = *(const float4*)(row+8);
    float u = xib[(size_t)ps*DIC];
    float dt = bdt + q0.x*wdt.x + q0.y*wdt.y + q0.z*wdt.z + q0.w*wdt.w;
    dt = softplusf_(dt);
    sumd += dt;
    float du = dt*u;
    float Bv[NS] = {q1.x,q1.y,q1.z,q1.w,q2.x,q2.y,q2.z,q2.w};
    #pragma unroll
    for (int n=0;n<NS;++n)
      h[n] = h[n]*exp2f(dt*Arow[n]) + du*Bv[n];
  }
  size_t base = ((size_t)((b*KD+k)*NCH + ch)*NS)*DIC + c;
  #pragma unroll
  for (int n=0;n<NS;++n) hp[base + n*DIC] = h[n];
  #pragma unroll
  for (int n=0;n<NS;++n) cumA[base + n*DIC] = exp2f(sumd*Arow[n]);
}

// ---------- P2: prefix over chunk summaries, thread per (bk,n,c); hp becomes h_in ----------
__global__ void k_p2(const float* __restrict__ cumA, float* __restrict__ hp){
  int idx = blockIdx.x*256 + threadIdx.x;
  if (idx >= BB*KD*NS*DIC) return;
  int c = idx % DIC; int n = (idx/DIC) % NS; int bk = idx/(DIC*NS);
  float h = 0.f;
  #pragma unroll 4
  for (int ch=0; ch<NCH; ++ch){
    size_t base = ((size_t)(bk*NCH+ch)*NS + n)*DIC + c;
    float a = cumA[base];
    float pp = hp[base];
    hp[base] = h;
    h = a*h + pp;
  }
}

// ---------- P3: replay chunks, accumulate into y_t [b][p][c] with coalesced atomics ----------
__global__ void k_p3(const float* __restrict__ xi_t, const float* __restrict__ xdbl,
                     const float* __restrict__ dtpw, const float* __restrict__ dtpb,
                     const float* __restrict__ alog, const float* __restrict__ Dsv,
                     const float* __restrict__ hin, float* __restrict__ y_t){
  int idx = blockIdx.x*256 + threadIdx.x;
  if (idx >= BB*KD*NCH*DIC) return;
  int b,k,ch,c; scan_decode(idx,b,k,ch,c);
  float Arow[NS];
  #pragma unroll
  for (int n=0;n<NS;++n) Arow[n] = -__expf(alog[(k*DIC+c)*NS+n]) * L2E;
  float4 wdt = *(const float4*)(dtpw + (k*DIC+c)*RD);
  float bdt = dtpb[k*DIC+c];
  float Dv = Dsv[k*DIC+c];
  const float* xd = xdbl + (size_t)(b*KD+k)*LL*20;
  const float* xib = xi_t + (size_t)b*LL*DIC + c;
  float* yb = y_t + (size_t)b*LL*DIC + c;
  float h[NS];
  size_t base = ((size_t)((b*KD+k)*NCH + ch)*NS)*DIC + c;
  #pragma unroll
  for (int n=0;n<NS;++n) h[n] = hin[base + n*DIC];
  #pragma unroll 2
  for (int t=0; t<TS; ++t){
    int l = ch*TS + t;
    int ps = dirmap(k,l);
    const float* row = xd + (size_t)ps*20;
    float4 q0 = *(const float4*)(row);
    float4 q1 = *(const float4*)(row+4);
    float4 q2 = *(const float4*)(row+8);
    float4 q3 = *(const float4*)(row+12);
    float4 q4 = *(const float4*)(row+16);
    float u = xib[(size_t)ps*DIC];
    float dt = bdt + q0.x*wdt.x + q0.y*wdt.y + q0.z*wdt.z + q0.w*wdt.w;
    dt = softplusf_(dt);
    float du = dt*u;
    float Bv[NS] = {q1.x,q1.y,q1.z,q1.w,q2.x,q2.y,q2.z,q2.w};
    float Cv[NS] = {q3.x,q3.y,q3.z,q3.w,q4.x,q4.y,q4.z,q4.w};
    float y = 0.f;
    #pragma unroll
    for (int n=0;n<NS;++n){
      h[n] = h[n]*exp2f(dt*Arow[n]) + du*Bv[n];
      y += h[n]*Cv[n];
    }
    y += u*Dv;
    atomicAdd(yb + (size_t)ps*DIC, y);
  }
}

// ---------- out-proj fused with LN(y)*ong+onb and *silu(z); 512 threads, 8 ocg x 9 oc ----------
__global__ void k_oproj(const float* __restrict__ y_t, const float* __restrict__ z_t,
                        const float* __restrict__ ong, const float* __restrict__ onb,
                        const float* __restrict__ opw, float* __restrict__ xout){
  __shared__ float ly[DIC*65];
  __shared__ float red1[8][64], red2[8][64];
  __shared__ float lmu[64], lrs[64];
  int bid = blockIdx.x;              // BB * 64 tiles
  int tile = bid & 63; int b = bid >> 6;
  int pstart = tile*64;
  const float* src = y_t + ((size_t)b*LL + pstart)*DIC;
  for (int i = threadIdx.x; i < 64*DIC; i += 512){
    int px = i / DIC; int d = i - px*DIC;
    ly[d*65 + px] = src[i];
  }
  __syncthreads();
  int px = threadIdx.x & 63;
  int grp = threadIdx.x >> 6;        // 0..7, wave index
  {
    float s=0.f, q=0.f;
    for (int d=grp*18; d<grp*18+18; ++d){
      float v = ly[d*65+px]; s += v; q += v*v;
    }
    red1[grp][px]=s; red2[grp][px]=q;
  }
  __syncthreads();
  if (grp == 0){
    float st=0.f, qt=0.f;
    #pragma unroll
    for (int g=0;g<8;++g){ st += red1[g][px]; qt += red2[g][px]; }
    float mu = st*(1.f/DIC);
    float var = qt*(1.f/DIC) - mu*mu;
    lmu[px] = mu;
    lrs[px] = rsqrtf(var + 1e-5f);
  }
  __syncthreads();
  const float* zsrc = z_t + ((size_t)b*LL + pstart)*DIC;
  for (int i = threadIdx.x; i < 64*DIC; i += 512){
    int ppx = i / DIC; int d = i - ppx*DIC;
    float zv = zsrc[i];
    float v = ly[d*65+ppx];
    ly[d*65+ppx] = ((v - lmu[ppx])*lrs[ppx]*ong[d] + onb[d]) * siluf_(zv);
  }
  __syncthreads();
  int ocg = __builtin_amdgcn_readfirstlane(grp);  // 0..7 wave-uniform
  float acc[9];
  #pragma unroll
  for (int j=0;j<9;++j) acc[j]=0.f;
  const float* wb = opw + (size_t)ocg*9*DIC;
  #pragma unroll 4
  for (int d=0; d<DIC; ++d){
    float a = ly[d*65 + px];
    #pragma unroll
    for (int j=0;j<9;++j) acc[j] += a * wb[(size_t)j*DIC + d];
  }
  #pragma unroll
  for (int j=0;j<9;++j)
    xout[((size_t)(b*DMC + ocg*9 + j)<<12) + pstart + px] = acc[j];
}

// ---------- groupnorm pass A: partial stats -> atomic (sum, sumsq) per (b,group) ----------
__global__ void k_gnA(const float* __restrict__ x, float* __restrict__ stats){
  __shared__ float s1[256], s2[256];
  int bid = blockIdx.x;    // BB*GRP*16
  int t = bid & 15; int r = bid >> 4; int gr = r % GRP; int b = r / GRP;
  float ls=0.f, lq=0.f;
  #pragma unroll
  for (int it=0; it<6; ++it){
    int i = t*1536 + it*256 + threadIdx.x;   // i in [0, 24576)
    int c = gr*6 + (i>>12); int p = i & 4095;
    float v = x[((size_t)(b*DMC+c)<<12)+p];
    ls += v; lq += v*v;
  }
  s1[threadIdx.x]=ls; s2[threadIdx.x]=lq; __syncthreads();
  for (int s=128; s>0; s>>=1){
    if (threadIdx.x < s){ s1[threadIdx.x]+=s1[threadIdx.x+s]; s2[threadIdx.x]+=s2[threadIdx.x+s]; }
    __syncthreads();
  }
  if (threadIdx.x == 0){
    atomicAdd(stats + (b*GRP+gr)*2,     s1[0]);
    atomicAdd(stats + (b*GRP+gr)*2 + 1, s2[0]);
  }
}

// ---------- groupnorm pass B: per-(b,c) scale/shift coefficients ----------
__global__ void k_gnAB(const float* __restrict__ stats, const float* __restrict__ g,
                       const float* __restrict__ bta, float* __restrict__ gnab){
  int idx = blockIdx.x*256 + threadIdx.x;
  if (idx >= BB*DMC) return;
  int c = idx % DMC; int b = idx / DMC; int gr = c / 6;
  float s = stats[(b*GRP+gr)*2];
  float q = stats[(b*GRP+gr)*2 + 1];
  const float inv = 1.f/(6.f*LL);
  float mu = s*inv;
  float var = q*inv - mu*mu;
  float rs = rsqrtf(var + 1e-5f);
  float A = rs*g[c];
  gnab[idx] = A;
  gnab[BB*DMC + idx] = bta[c] - mu*A;
}

// ---------- dense1: l1( gn(x) ) via AB coefficients, 2 oc/thread, no lrelu stored ----------
__global__ void k_dense1(const float* __restrict__ xin, const float* __restrict__ gnab,
                         const float* __restrict__ w, const float* __restrict__ bias,
                         float* __restrict__ xout){
  int bid = blockIdx.x;
  int t = bid & 15; int r = bid >> 4; int eg = r % 36; int b = r / 36;
  int p = t*256 + threadIdx.x;
  float acc[2] = { bias[eg*2], bias[eg*2+1] };
  const float* Aab = gnab + b*DMC;
  const float* Bab = gnab + BB*DMC + b*DMC;
  for (int c0=0; c0<DMC; c0+=4){
    float a[4];
    #pragma unroll
    for (int q=0;q<4;++q){
      float v = xin[((size_t)(b*DMC+c0+q)<<12)+p];
      a[q] = v*Aab[c0+q] + Bab[c0+q];
    }
    #pragma unroll
    for (int j=0;j<2;++j){
      float4 w0 = *(const float4*)(w + (eg*2+j)*DMC + c0);
      acc[j] += a[0]*w0.x + a[1]*w0.y + a[2]*w0.z + a[3]*w0.w;
    }
  }
  #pragma unroll
  for (int j=0;j<2;++j)
    xout[((size_t)(b*DMC+eg*2+j)<<12)+p] = acc[j];
}

// ---------- dense2: l2( lrelu(tmp) ), 2 oc/thread ----------
__global__ void k_dense2(const float* __restrict__ xin, const float* __restrict__ w,
                         const float* __restrict__ bias, float* __restrict__ xout,
                         float* __restrict__ pad_out){
  int bid = blockIdx.x;
  int t = bid & 15; int r = bid >> 4; int eg = r % 36; int b = r / 36;
  int p = t*256 + threadIdx.x;
  float acc[2] = { bias[eg*2], bias[eg*2+1] };
  for (int c0=0; c0<DMC; c0+=4){
    float a[4];
    #pragma unroll
    for (int q=0;q<4;++q){
      float v = xin[((size_t)(b*DMC+c0+q)<<12)+p];
      a[q] = v >= 0.f ? v : 0.04f*v;
    }
    #pragma unroll
    for (int j=0;j<2;++j){
      float4 w0 = *(const float4*)(w + (eg*2+j)*DMC + c0);
      acc[j] += a[0]*w0.x + a[1]*w0.y + a[2]*w0.z + a[3]*w0.w;
    }
  }
  #pragma unroll
  for (int j=0;j<2;++j){
    xout[((size_t)(b*DMC+eg*2+j)<<12)+p] = acc[j];
    if (pad_out) pad_out[(size_t)(b*DMC+eg*2+j)*PP + padidx(p)] = acc[j];
  }
}

// ---------- shrink conv pass A: 24 ic-groups of 3, 6 oc partials, atomic ----------
__global__ void k_shrinkA(const float* __restrict__ x_pad, const float* __restrict__ w,
                          float* __restrict__ pacc){
  int bid = blockIdx.x;   // b(4) * icg(24) * tile(16)
  int t = bid & 15; int r = bid >> 4; int icg = r % 24; int b = r / 24;
  int p = t*256 + threadIdx.x;
  int pb = padidx(p);
  float acc[6] = {0.f,0.f,0.f,0.f,0.f,0.f};
  const float* ipb = x_pad + (size_t)b*DMC*PP + pb;
  #pragma unroll
  for (int ii=0; ii<3; ++ii){
    int ic = icg*3 + ii;
    const float* ip = ipb + (size_t)ic*PP;
    float a[9]; LOAD9(ip, a);
    #pragma unroll
    for (int o=0;o<6;++o){
      const float* wp = w + (o*DMC+ic)*9;
      float s = 0.f;
      #pragma unroll
      for (int q=0;q<9;++q) s += a[q]*wp[q];
      acc[o] += s;
    }
  }
  #pragma unroll
  for (int o=0;o<6;++o)
    atomicAdd(pacc + ((size_t)(b*CI+o)<<12)+p, acc[o]);
}

// ---------- shrink pass B: bias + sigmoid ----------
__global__ void k_sig(const float* __restrict__ pacc, const float* __restrict__ bias,
                      float* __restrict__ out){
  int idx = blockIdx.x*256 + threadIdx.x;
  if (idx >= BB*CI*LL) return;
  int o = (idx>>12) % CI;
  out[idx] = sigmoidf_(pacc[idx] + bias[o]);
}

extern "C" void kernel_launch(void* const* d_in, const int* in_sizes, int n_in,
                              void* d_out, int out_size, void* d_ws, size_t ws_size,
                              hipStream_t stream){
  const float* image = (const float*)d_in[0];
  const float* cb_w1 = (const float*)d_in[1];
  const float* cb_b1 = (const float*)d_in[2];
  const float* cb_w2 = (const float*)d_in[3];
  const float* cb_b2 = (const float*)d_in[4];
  const float* cb_ws = (const float*)d_in[5];
  const float* cb_bs = (const float*)d_in[6];
  const float* in_w  = (const float*)d_in[7];
  const float* dw_w  = (const float*)d_in[8];
  const float* dw_b  = (const float*)d_in[9];
  const float* xp_w  = (const float*)d_in[10];
  const float* dtp_w = (const float*)d_in[11];
  const float* dtp_b = (const float*)d_in[12];
  const float* A_logs= (const float*)d_in[13];
  const float* Ds    = (const float*)d_in[14];
  const float* ong   = (const float*)d_in[15];
  const float* onb   = (const float*)d_in[16];
  const float* op_w  = (const float*)d_in[17];
  const float* gn_g  = (const float*)d_in[18];
  const float* gn_b  = (const float*)d_in[19];
  const float* l1_w  = (const float*)d_in[20];
  const float* l1_b  = (const float*)d_in[21];
  const float* l2_w  = (const float*)d_in[22];
  const float* l2_b  = (const float*)d_in[23];
  const float* sh_w  = (const float*)d_in[24];
  const float* sh_b  = (const float*)d_in[25];

  const size_t SZ_X  = (size_t)BB*DMC*LL;        // 1,179,648
  const size_t SZ_C  = (size_t)BB*DIC*LL;        // 2,359,296
  const size_t SZ_XD = (size_t)BB*KD*20*LL;      // 1,310,720
  const size_t SZ_IP = (size_t)BB*CI*PP;         // img_pad
  const size_t SZ_TP = (size_t)BB*DMC*PP;        // tmp_pad (= xfin_pad)
  const size_t SZ_ZP = (size_t)BB*DIC*PP;        // xz_pad

  float* ws = (float*)d_ws;
  size_t off = 0;
  float* x     = ws + off; off += SZ_X;
  float* tmp   = ws + off; off += SZ_X;   // dense l1 out; later shrink pacc
  float* z_t   = ws + off; off += SZ_C;
  float* xi_t  = ws + off; off += SZ_C;
  float* xdbl  = ws + off; off += SZ_XD;
  float* cumA  = ws + off; off += SZ_C;   // aliased: cumA (p1/p2) then y_t (p3..oproj)
  float* hp    = ws + off; off += SZ_C;
  float* pads  = ws + off;
  float* img_pad = pads;
  float* tmp_pad = img_pad + SZ_IP;       // also xfin_pad for shrink
  float* xz_pad  = tmp_pad + SZ_TP;
  off += SZ_IP + SZ_TP + SZ_ZP;
  float* gnstats = ws + off; off += 2*BB*GRP;      // 96
  float* gnab    = ws + off; off += 2*BB*DMC;      // 576
  if (ws_size < off*sizeof(float)) return;
  float* y_t = cumA;

  dim3 blk(256);
  const int NPLANES = BB*CI + BB*DMC + BB*DIC;   // 888 padded planes

  k_halo<<<dim3(NPLANES), blk, 0, stream>>>(pads, NPLANES);
  k_pad_img<<<dim3(BB*CI*16), blk, 0, stream>>>(image, img_pad);
  k_conv1<<<dim3(BB*DMC*16), blk, 0, stream>>>(img_pad, cb_w1, cb_b1, tmp_pad);
  k_conv2init<<<dim3(BB*18*16), blk, 0, stream>>>(image, cb_b2, cb_ws, cb_bs, x);
  k_conv2<<<dim3(BB*2*18*16), blk, 0, stream>>>(tmp_pad, cb_w2, x);

  for (int i=0; i<NLAYER; ++i){
    const float* in_w_i  = in_w  + (size_t)i*2*DIC*DMC;
    const float* dw_w_i  = dw_w  + (size_t)i*DIC*9;
    const float* dw_b_i  = dw_b  + (size_t)i*DIC;
    const float* xp_w_i  = xp_w  + (size_t)i*KD*20*DIC;
    const float* dtp_w_i = dtp_w + (size_t)i*KD*DIC*RD;
    const float* dtp_b_i = dtp_b + (size_t)i*KD*DIC;
    const float* alog_i  = A_logs+ (size_t)i*KD*DIC*NS;
    const float* Ds_i    = Ds    + (size_t)i*KD*DIC;
    const float* ong_i   = ong   + (size_t)i*DIC;
    const float* onb_i   = onb   + (size_t)i*DIC;
    const float* op_w_i  = op_w  + (size_t)i*DMC*DIC;
    const float* gn_g_i  = gn_g  + (size_t)i*DMC;
    const float* gn_b_i  = gn_b  + (size_t)i*DMC;
    const float* l1_w_i  = l1_w  + (size_t)i*DMC*DMC;
    const float* l1_b_i  = l1_b  + (size_t)i*DMC;
    const float* l2_w_i  = l2_w  + (size_t)i*DMC*DMC;
    const float* l2_b_i  = l2_b  + (size_t)i*DMC;

    k_xz  <<<dim3(BB*36*16), blk, 0, stream>>>(x, in_w_i, xz_pad, z_t, (i==0)?1:0);
    k_dw  <<<dim3(BB*DIC*16), blk, 0, stream>>>(xz_pad, dw_w_i, dw_b_i, xi_t);
    k_xdbl<<<dim3(BB*10*KD*16), blk, 0, stream>>>(xi_t, xp_w_i, xdbl);
    k_p1  <<<dim3(BB*KD*NCH*DIC/256), blk, 0, stream>>>(xi_t, xdbl, dtp_w_i, dtp_b_i, alog_i, cumA, hp);
    k_p2  <<<dim3(BB*KD*NS*DIC/256), blk, 0, stream>>>(cumA, hp);
    hipMemsetAsync(y_t, 0, SZ_C*sizeof(float), stream);
    k_p3  <<<dim3(BB*KD*NCH*DIC/256), blk, 0, stream>>>(xi_t, xdbl, dtp_w_i, dtp_b_i, alog_i, Ds_i, hp, y_t);
    k_oproj<<<dim3(BB*64), dim3(512), 0, stream>>>(y_t, z_t, ong_i, onb_i, op_w_i, x);
    hipMemsetAsync(gnstats, 0, 2*BB*GRP*sizeof(float), stream);
    k_gnA <<<dim3(BB*GRP*16), blk, 0, stream>>>(x, gnstats);
    k_gnAB<<<dim3(2), blk, 0, stream>>>(gnstats, gn_g_i, gn_b_i, gnab);
    k_dense1<<<dim3(BB*36*16), blk, 0, stream>>>(x, gnab, l1_w_i, l1_b_i, tmp);
    k_dense2<<<dim3(BB*36*16), blk, 0, stream>>>(tmp, l2_w_i, l2_b_i, x,
                                                 (i==NLAYER-1) ? tmp_pad : (float*)nullptr);
  }

  // shrink: split-ic partials into tmp (reused as pacc), then bias+sigmoid
  hipMemsetAsync(tmp, 0, (size_t)BB*CI*LL*sizeof(float), stream);
  k_shrinkA<<<dim3(BB*24*16), blk, 0, stream>>>(tmp_pad, sh_w, tmp);
  k_sig<<<dim3((BB*CI*LL+255)/256), blk, 0, stream>>>(tmp, sh_b, (float*)d_out);
}

// Round 8
// 502.062 us; speedup vs baseline: 1.0731x; 1.0731x over previous
//
#include <hip/hip_runtime.h>
#include <math.h>

#define BB 4
#define CI 6
#define LL 4096
#define DMC 72
#define DIC 144
#define KD 4
#define NS 8
#define RD 4
#define NLAYER 2
#define GRP 12
#define NCH 256   // chunks per scan
#define TS 16     // steps per chunk
#define PP 4356   // padded 66x66 plane
#define L2E 1.4426950408889634f

__device__ __forceinline__ float sigmoidf_(float x){ return 1.f/(1.f+__expf(-x)); }
__device__ __forceinline__ float siluf_(float x){ return x*sigmoidf_(x); }
// fast softplus: |err| << 2e-3 tolerance
__device__ __forceinline__ float softplusf_(float x){
  return fmaxf(x,0.f) + __logf(1.f + __expf(-fabsf(x)));
}

__device__ __forceinline__ int padidx(int p){ return 66*(p>>6) + (p&63) + 67; }

// spatial position p (row-major h*64+w) for scan index l of direction k
__device__ __forceinline__ int dirmap(int k, int l){
  switch(k & 3){
    case 0: return l;
    case 1: return ((l & 63) << 6) | (l >> 6);
    case 2: return (LL-1) - l;
    default: { int m = (LL-1) - l; return ((m & 63) << 6) | (m >> 6); }
  }
}

#define LOAD9(ip, a) do { \
  a[0]=(ip)[-67]; a[1]=(ip)[-66]; a[2]=(ip)[-65]; \
  a[3]=(ip)[-1];  a[4]=(ip)[0];   a[5]=(ip)[1];   \
  a[6]=(ip)[65];  a[7]=(ip)[66];  a[8]=(ip)[67];  } while(0)

// ---------- zero halos of all padded planes ----------
__global__ void k_halo(float* __restrict__ pads, int nplanes){
  int plane = blockIdx.x;
  if (plane >= nplanes) return;
  int t = threadIdx.x;
  if (t >= 260) return;
  float* pl = pads + (size_t)plane*PP;
  int off;
  if (t < 132){
    int row = (t < 66) ? 0 : 65;
    int col = (t < 66) ? t : t-66;
    off = row*66 + col;
  } else {
    int j = t - 132;
    int col = (j < 64) ? 0 : 65;
    int row = 1 + (j & 63);
    off = row*66 + col;
  }
  pl[off] = 0.f;
}

// ---------- pad copy of the input image ----------
__global__ void k_pad_img(const float* __restrict__ img, float* __restrict__ img_pad){
  int idx = blockIdx.x*256 + threadIdx.x;
  if (idx >= BB*CI*LL) return;
  int p = idx & 4095; int bc = idx >> 12;
  img_pad[(size_t)bc*PP + padidx(p)] = img[idx];
}

// ---------- conv 6->72 3x3 + lrelu(0.01); padded in, padded out ----------
__global__ void k_conv1(const float* __restrict__ img_pad, const float* __restrict__ w,
                        const float* __restrict__ bias, float* __restrict__ tmp_pad){
  int bid = blockIdx.x;
  int t = bid & 15; int r = bid >> 4; int o = r % DMC; int b = r / DMC;
  int p = t*256 + threadIdx.x;
  int pb = padidx(p);
  float acc = bias[o];
  const float* wb = w + o*CI*9;
  #pragma unroll
  for (int ic=0; ic<CI; ++ic){
    const float* ip = img_pad + (size_t)(b*CI+ic)*PP + pb;
    float a[9]; LOAD9(ip, a);
    #pragma unroll
    for (int q=0;q<9;++q) acc += a[q]*wb[ic*9+q];
  }
  tmp_pad[(size_t)(b*DMC+o)*PP + pb] = acc >= 0.f ? acc : 0.01f*acc;
}

// ---------- conv2 init: bias + 1x1 shortcut -> x (pre-lrelu) ----------
__global__ void k_conv2init(const float* __restrict__ img, const float* __restrict__ b2,
                            const float* __restrict__ wsc, const float* __restrict__ bsc,
                            float* __restrict__ xout){
  int bid = blockIdx.x;
  int t = bid & 15; int r = bid >> 4; int og = r % 18; int b = r / 18;
  int p = t*256 + threadIdx.x;
  float acc[4];
  #pragma unroll
  for (int j=0;j<4;++j) acc[j] = b2[og*4+j] + bsc[og*4+j];
  #pragma unroll
  for (int ic=0; ic<CI; ++ic){
    float v = img[((b*CI+ic)<<12)+p];
    #pragma unroll
    for (int j=0;j<4;++j) acc[j] += v * wsc[(og*4+j)*CI+ic];
  }
  #pragma unroll
  for (int j=0;j<4;++j)
    xout[((b*DMC+og*4+j)<<12)+p] = acc[j];
}

// ---------- conv 72->72 3x3 partials, ic-split x2, atomic accumulate (no lrelu) ----------
__global__ void k_conv2(const float* __restrict__ tmp_pad,
                        const float* __restrict__ w2, float* __restrict__ xout){
  int bid = blockIdx.x;
  int t = bid & 15; int r = bid >> 4; int og = r % 18; r /= 18;
  int icg = r & 1; int b = r >> 1;
  int p = t*256 + threadIdx.x;
  int pb = padidx(p);
  float acc[4] = {0.f,0.f,0.f,0.f};
  const float* ipb = tmp_pad + (size_t)b*DMC*PP + pb;
  const float* wb  = w2 + (size_t)(og*4)*DMC*9;
  #pragma unroll 2
  for (int ii=0; ii<36; ++ii){
    int ic = icg*36 + ii;
    const float* ip = ipb + (size_t)ic*PP;
    float a[9]; LOAD9(ip, a);
    const float* wp = wb + ic*9;
    #pragma unroll
    for (int j=0;j<4;++j){
      float s = 0.f;
      #pragma unroll
      for (int q=0;q<9;++q) s += a[q]*wp[(size_t)j*DMC*9 + q];
      acc[j] += s;
    }
  }
  #pragma unroll
  for (int j=0;j<4;++j)
    atomicAdd(xout + ((b*DMC+og*4+j)<<12)+p, acc[j]);
}

// ---------- xz (optional lrelu on load): 144 ch -> padded planes; z -> z_t [b][p][c] ----------
__global__ void k_xz(const float* __restrict__ x, const float* __restrict__ inw,
                     float* __restrict__ xz_pad, float* __restrict__ z_t, int relu){
  int bid = blockIdx.x;
  int t = bid & 15; int r = bid >> 4; int eg = r % 36; int b = r / 36;
  int p = t*256 + threadIdx.x;
  float acc[8] = {0.f,0.f,0.f,0.f,0.f,0.f,0.f,0.f};
  for (int c0=0; c0<DMC; c0+=4){
    float a[4];
    #pragma unroll
    for (int q=0;q<4;++q) a[q] = x[((b*DMC+c0+q)<<12)+p];
    if (relu){
      #pragma unroll
      for (int q=0;q<4;++q) a[q] = a[q] >= 0.f ? a[q] : 0.01f*a[q];
    }
    #pragma unroll
    for (int j=0;j<8;++j){
      float4 w = *(const float4*)(inw + (eg*8+j)*DMC + c0);
      acc[j] += a[0]*w.x + a[1]*w.y + a[2]*w.z + a[3]*w.w;
    }
  }
  if (eg < 18){
    int pb = padidx(p);
    #pragma unroll
    for (int j=0;j<8;++j) xz_pad[(size_t)(b*DIC+eg*8+j)*PP + pb] = acc[j];
  } else {
    float* zb = z_t + ((size_t)b*LL+p)*DIC + (eg*8-DIC);
    *(float4*)(zb)   = make_float4(acc[0],acc[1],acc[2],acc[3]);
    *(float4*)(zb+4) = make_float4(acc[4],acc[5],acc[6],acc[7]);
  }
}

// ---------- depthwise 3x3 + bias + silu -> xi_t [b][p][c] ----------
__global__ void k_dw(const float* __restrict__ xz_pad, const float* __restrict__ dww,
                     const float* __restrict__ dwb, float* __restrict__ xi_t){
  int bid = blockIdx.x;
  int t = bid & 15; int r = bid >> 4; int c = r % DIC; int b = r / DIC;
  int p = t*256 + threadIdx.x;
  int pb = padidx(p);
  const float* ip = xz_pad + (size_t)(b*DIC+c)*PP + pb;
  const float* wp = dww + c*9;
  float a[9]; LOAD9(ip, a);
  float acc = dwb[c];
  #pragma unroll
  for (int q=0;q<9;++q) acc += a[q]*wp[q];
  xi_t[((size_t)b*LL+p)*DIC + c] = siluf_(acc);
}

// ---------- x_dbl [bk][p][20]; 4 parts of 5 ch; thread=(b,part,k,ptile) ----------
__global__ void k_xdbl(const float* __restrict__ xi_t, const float* __restrict__ xpw,
                       float* __restrict__ xdbl){
  int bid = blockIdx.x;
  int t = bid & 15; int r = bid >> 4;
  int kk = r & 3; r >>= 2; int part = r & 3; int b = r >> 2;
  int p = t*256 + threadIdx.x;
  const float* xib = xi_t + ((size_t)b*LL + p)*DIC;
  const float* wk = xpw + (size_t)(kk*20 + part*5)*DIC;
  float acc[5] = {0.f,0.f,0.f,0.f,0.f};
  for (int d=0; d<DIC; d+=4){
    float4 v = *(const float4*)(xib + d);
    #pragma unroll
    for (int c=0;c<5;++c){
      float4 w = *(const float4*)(wk + (size_t)c*DIC + d);
      acc[c] += v.x*w.x + v.y*w.y + v.z*w.z + v.w*w.w;
    }
  }
  float* dst = xdbl + ((size_t)(b*KD+kk)*LL + p)*20 + part*5;
  #pragma unroll
  for (int c=0;c<5;++c) dst[c] = acc[c];
}

__device__ __forceinline__ void scan_decode(int idx, int& b, int& k, int& ch, int& c){
  c = idx % DIC;
  int r = idx / DIC;
  ch = r % NCH;
  r /= NCH;
  k = r & 3; b = r >> 2;
}

// ---------- P1: per-chunk summaries (cumA, partial state), layout [bk][ch][n][c] ----------
__global__ void k_p1(const float* __restrict__ xi_t, const float* __restrict__ xdbl,
                     const float* __restrict__ dtpw, const float* __restrict__ dtpb,
                     const float* __restrict__ alog,
                     float* __restrict__ cumA, float* __restrict__ hp){
  int idx = blockIdx.x*256 + threadIdx.x;
  if (idx >= BB*KD*NCH*DIC) return;
  int b,k,ch,c; scan_decode(idx,b,k,ch,c);
  float Arow[NS];   // pre-scaled by log2(e): exp(dt*A) = exp2(dt*Arow)
  #pragma unroll
  for (int n=0;n<NS;++n) Arow[n] = -__expf(alog[(k*DIC+c)*NS+n]) * L2E;
  float4 wdt = *(const float4*)(dtpw + (k*DIC+c)*RD);
  float bdt = dtpb[k*DIC+c];
  const float* xd = xdbl + (size_t)(b*KD+k)*LL*20;
  const float* xib = xi_t + (size_t)b*LL*DIC + c;
  float h[NS];
  #pragma unroll
  for (int n=0;n<NS;++n) h[n]=0.f;
  float sumd = 0.f;
  #pragma unroll 4
  for (int t=0; t<TS; ++t){
    int l = ch*TS + t;
    int ps = dirmap(k,l);
    const float* row = xd + (size_t)ps*20;
    float4 q0 = *(const float4*)(row);
    float4 q1 = *(const float4*)(row+4);
    float4 q2 = *(const float4*)(row+8);
    float u = xib[(size_t)ps*DIC];
    float dt = bdt + q0.x*wdt.x + q0.y*wdt.y + q0.z*wdt.z + q0.w*wdt.w;
    dt = softplusf_(dt);
    sumd += dt;
    float du = dt*u;
    float Bv[NS] = {q1.x,q1.y,q1.z,q1.w,q2.x,q2.y,q2.z,q2.w};
    #pragma unroll
    for (int n=0;n<NS;++n)
      h[n] = h[n]*exp2f(dt*Arow[n]) + du*Bv[n];
  }
  size_t base = ((size_t)((b*KD+k)*NCH + ch)*NS)*DIC + c;
  #pragma unroll
  for (int n=0;n<NS;++n) hp[base + n*DIC] = h[n];
  #pragma unroll
  for (int n=0;n<NS;++n) cumA[base + n*DIC] = exp2f(sumd*Arow[n]);
}

// ---------- P2: prefix over chunk summaries; zeroes cumA (=y_t) as it reads ----------
__global__ void k_p2(float* __restrict__ cumA, float* __restrict__ hp){
  int idx = blockIdx.x*256 + threadIdx.x;
  if (idx >= BB*KD*NS*DIC) return;
  int c = idx % DIC; int n = (idx/DIC) % NS; int bk = idx/(DIC*NS);
  float h = 0.f;
  #pragma unroll 4
  for (int ch=0; ch<NCH; ++ch){
    size_t base = ((size_t)(bk*NCH+ch)*NS + n)*DIC + c;
    float a = cumA[base];
    float pp = hp[base];
    cumA[base] = 0.f;          // cumA aliases y_t: zero for p3's atomics
    hp[base] = h;
    h = a*h + pp;
  }
}

// ---------- P3: replay chunks, accumulate into y_t [b][p][c] with coalesced atomics ----------
__global__ void k_p3(const float* __restrict__ xi_t, const float* __restrict__ xdbl,
                     const float* __restrict__ dtpw, const float* __restrict__ dtpb,
                     const float* __restrict__ alog, const float* __restrict__ Dsv,
                     const float* __restrict__ hin, float* __restrict__ y_t){
  int idx = blockIdx.x*256 + threadIdx.x;
  if (idx >= BB*KD*NCH*DIC) return;
  int b,k,ch,c; scan_decode(idx,b,k,ch,c);
  float Arow[NS];
  #pragma unroll
  for (int n=0;n<NS;++n) Arow[n] = -__expf(alog[(k*DIC+c)*NS+n]) * L2E;
  float4 wdt = *(const float4*)(dtpw + (k*DIC+c)*RD);
  float bdt = dtpb[k*DIC+c];
  float Dv = Dsv[k*DIC+c];
  const float* xd = xdbl + (size_t)(b*KD+k)*LL*20;
  const float* xib = xi_t + (size_t)b*LL*DIC + c;
  float* yb = y_t + (size_t)b*LL*DIC + c;
  float h[NS];
  size_t base = ((size_t)((b*KD+k)*NCH + ch)*NS)*DIC + c;
  #pragma unroll
  for (int n=0;n<NS;++n) h[n] = hin[base + n*DIC];
  #pragma unroll 4
  for (int t=0; t<TS; ++t){
    int l = ch*TS + t;
    int ps = dirmap(k,l);
    const float* row = xd + (size_t)ps*20;
    float4 q0 = *(const float4*)(row);
    float4 q1 = *(const float4*)(row+4);
    float4 q2 = *(const float4*)(row+8);
    float4 q3 = *(const float4*)(row+12);
    float4 q4 = *(const float4*)(row+16);
    float u = xib[(size_t)ps*DIC];
    float dt = bdt + q0.x*wdt.x + q0.y*wdt.y + q0.z*wdt.z + q0.w*wdt.w;
    dt = softplusf_(dt);
    float du = dt*u;
    float Bv[NS] = {q1.x,q1.y,q1.z,q1.w,q2.x,q2.y,q2.z,q2.w};
    float Cv[NS] = {q3.x,q3.y,q3.z,q3.w,q4.x,q4.y,q4.z,q4.w};
    float y = 0.f;
    #pragma unroll
    for (int n=0;n<NS;++n){
      h[n] = h[n]*exp2f(dt*Arow[n]) + du*Bv[n];
      y += h[n]*Cv[n];
    }
    y += u*Dv;
    atomicAdd(yb + (size_t)ps*DIC, y);
  }
}

// ---------- out-proj fused with LN(y)*ong+onb and *silu(z); 512 threads, 8 ocg x 9 oc ----------
__global__ void k_oproj(const float* __restrict__ y_t, const float* __restrict__ z_t,
                        const float* __restrict__ ong, const float* __restrict__ onb,
                        const float* __restrict__ opw, float* __restrict__ xout,
                        float* __restrict__ gnstats){
  __shared__ float ly[DIC*65];
  __shared__ float red1[8][64], red2[8][64];
  __shared__ float lmu[64], lrs[64];
  int bid = blockIdx.x;              // BB * 64 tiles
  if (bid == 0 && threadIdx.x < 2*BB*GRP) gnstats[threadIdx.x] = 0.f;
  int tile = bid & 63; int b = bid >> 6;
  int pstart = tile*64;
  const float* src = y_t + ((size_t)b*LL + pstart)*DIC;
  for (int i = threadIdx.x; i < 64*DIC; i += 512){
    int px = i / DIC; int d = i - px*DIC;
    ly[d*65 + px] = src[i];
  }
  __syncthreads();
  int px = threadIdx.x & 63;
  int grp = threadIdx.x >> 6;        // 0..7, wave index
  {
    float s=0.f, q=0.f;
    for (int d=grp*18; d<grp*18+18; ++d){
      float v = ly[d*65+px]; s += v; q += v*v;
    }
    red1[grp][px]=s; red2[grp][px]=q;
  }
  __syncthreads();
  if (grp == 0){
    float st=0.f, qt=0.f;
    #pragma unroll
    for (int g=0;g<8;++g){ st += red1[g][px]; qt += red2[g][px]; }
    float mu = st*(1.f/DIC);
    float var = qt*(1.f/DIC) - mu*mu;
    lmu[px] = mu;
    lrs[px] = rsqrtf(var + 1e-5f);
  }
  __syncthreads();
  const float* zsrc = z_t + ((size_t)b*LL + pstart)*DIC;
  for (int i = threadIdx.x; i < 64*DIC; i += 512){
    int ppx = i / DIC; int d = i - ppx*DIC;
    float zv = zsrc[i];
    float v = ly[d*65+ppx];
    ly[d*65+ppx] = ((v - lmu[ppx])*lrs[ppx]*ong[d] + onb[d]) * siluf_(zv);
  }
  __syncthreads();
  int ocg = __builtin_amdgcn_readfirstlane(grp);  // 0..7 wave-uniform
  float acc[9];
  #pragma unroll
  for (int j=0;j<9;++j) acc[j]=0.f;
  const float* wb = opw + (size_t)ocg*9*DIC;
  #pragma unroll 4
  for (int d=0; d<DIC; ++d){
    float a = ly[d*65 + px];
    #pragma unroll
    for (int j=0;j<9;++j) acc[j] += a * wb[(size_t)j*DIC + d];
  }
  #pragma unroll
  for (int j=0;j<9;++j)
    xout[((size_t)(b*DMC + ocg*9 + j)<<12) + pstart + px] = acc[j];
}

// ---------- groupnorm pass A: partial stats -> atomic (sum, sumsq) per (b,group) ----------
__global__ void k_gnA(const float* __restrict__ x, float* __restrict__ stats){
  __shared__ float s1[256], s2[256];
  int bid = blockIdx.x;    // BB*GRP*16
  int t = bid & 15; int r = bid >> 4; int gr = r % GRP; int b = r / GRP;
  float ls=0.f, lq=0.f;
  #pragma unroll
  for (int it=0; it<6; ++it){
    int i = t*1536 + it*256 + threadIdx.x;   // i in [0, 24576)
    int c = gr*6 + (i>>12); int p = i & 4095;
    float v = x[((size_t)(b*DMC+c)<<12)+p];
    ls += v; lq += v*v;
  }
  s1[threadIdx.x]=ls; s2[threadIdx.x]=lq; __syncthreads();
  for (int s=128; s>0; s>>=1){
    if (threadIdx.x < s){ s1[threadIdx.x]+=s1[threadIdx.x+s]; s2[threadIdx.x]+=s2[threadIdx.x+s]; }
    __syncthreads();
  }
  if (threadIdx.x == 0){
    atomicAdd(stats + (b*GRP+gr)*2,     s1[0]);
    atomicAdd(stats + (b*GRP+gr)*2 + 1, s2[0]);
  }
}

// ---------- groupnorm pass B: per-(b,c) scale/shift coefficients ----------
__global__ void k_gnAB(const float* __restrict__ stats, const float* __restrict__ g,
                       const float* __restrict__ bta, float* __restrict__ gnab){
  int idx = blockIdx.x*256 + threadIdx.x;
  if (idx >= BB*DMC) return;
  int c = idx % DMC; int b = idx / DMC; int gr = c / 6;
  float s = stats[(b*GRP+gr)*2];
  float q = stats[(b*GRP+gr)*2 + 1];
  const float inv = 1.f/(6.f*LL);
  float mu = s*inv;
  float var = q*inv - mu*mu;
  float rs = rsqrtf(var + 1e-5f);
  float A = rs*g[c];
  gnab[idx] = A;
  gnab[BB*DMC + idx] = bta[c] - mu*A;
}

// ---------- dense1: l1( gn(x) ) via AB coefficients, 4 oc/thread ----------
__global__ void k_dense1(const float* __restrict__ xin, const float* __restrict__ gnab,
                         const float* __restrict__ w, const float* __restrict__ bias,
                         float* __restrict__ xout){
  int bid = blockIdx.x;
  int t = bid & 15; int r = bid >> 4; int eg = r % 18; int b = r / 18;
  int p = t*256 + threadIdx.x;
  float acc[4];
  #pragma unroll
  for (int j=0;j<4;++j) acc[j] = bias[eg*4+j];
  const float* Aab = gnab + b*DMC;
  const float* Bab = gnab + BB*DMC + b*DMC;
  for (int c0=0; c0<DMC; c0+=4){
    float a[4];
    #pragma unroll
    for (int q=0;q<4;++q){
      float v = xin[((size_t)(b*DMC+c0+q)<<12)+p];
      a[q] = v*Aab[c0+q] + Bab[c0+q];
    }
    #pragma unroll
    for (int j=0;j<4;++j){
      float4 w0 = *(const float4*)(w + (eg*4+j)*DMC + c0);
      acc[j] += a[0]*w0.x + a[1]*w0.y + a[2]*w0.z + a[3]*w0.w;
    }
  }
  #pragma unroll
  for (int j=0;j<4;++j)
    xout[((size_t)(b*DMC+eg*4+j)<<12)+p] = acc[j];
}

// ---------- dense2: l2( lrelu(tmp) ), 4 oc/thread ----------
__global__ void k_dense2(const float* __restrict__ xin, const float* __restrict__ w,
                         const float* __restrict__ bias, float* __restrict__ xout,
                         float* __restrict__ pad_out){
  int bid = blockIdx.x;
  int t = bid & 15; int r = bid >> 4; int eg = r % 18; int b = r / 18;
  int p = t*256 + threadIdx.x;
  float acc[4];
  #pragma unroll
  for (int j=0;j<4;++j) acc[j] = bias[eg*4+j];
  for (int c0=0; c0<DMC; c0+=4){
    float a[4];
    #pragma unroll
    for (int q=0;q<4;++q){
      float v = xin[((size_t)(b*DMC+c0+q)<<12)+p];
      a[q] = v >= 0.f ? v : 0.04f*v;
    }
    #pragma unroll
    for (int j=0;j<4;++j){
      float4 w0 = *(const float4*)(w + (eg*4+j)*DMC + c0);
      acc[j] += a[0]*w0.x + a[1]*w0.y + a[2]*w0.z + a[3]*w0.w;
    }
  }
  int pb = padidx(p);
  #pragma unroll
  for (int j=0;j<4;++j){
    xout[((size_t)(b*DMC+eg*4+j)<<12)+p] = acc[j];
    if (pad_out) pad_out[(size_t)(b*DMC+eg*4+j)*PP + pb] = acc[j];
  }
}

// ---------- shrink conv pass A: 24 ic-groups of 3, 6 oc partials, atomic ----------
__global__ void k_shrinkA(const float* __restrict__ x_pad, const float* __restrict__ w,
                          float* __restrict__ pacc){
  int bid = blockIdx.x;   // b(4) * icg(24) * tile(16)
  int t = bid & 15; int r = bid >> 4; int icg = r % 24; int b = r / 24;
  int p = t*256 + threadIdx.x;
  int pb = padidx(p);
  float acc[6] = {0.f,0.f,0.f,0.f,0.f,0.f};
  const float* ipb = x_pad + (size_t)b*DMC*PP + pb;
  #pragma unroll
  for (int ii=0; ii<3; ++ii){
    int ic = icg*3 + ii;
    const float* ip = ipb + (size_t)ic*PP;
    float a[9]; LOAD9(ip, a);
    #pragma unroll
    for (int o=0;o<6;++o){
      const float* wp = w + (o*DMC+ic)*9;
      float s = 0.f;
      #pragma unroll
      for (int q=0;q<9;++q) s += a[q]*wp[q];
      acc[o] += s;
    }
  }
  #pragma unroll
  for (int o=0;o<6;++o)
    atomicAdd(pacc + ((size_t)(b*CI+o)<<12)+p, acc[o]);
}

// ---------- shrink pass B: bias + sigmoid ----------
__global__ void k_sig(const float* __restrict__ pacc, const float* __restrict__ bias,
                      float* __restrict__ out){
  int idx = blockIdx.x*256 + threadIdx.x;
  if (idx >= BB*CI*LL) return;
  int o = (idx>>12) % CI;
  out[idx] = sigmoidf_(pacc[idx] + bias[o]);
}

extern "C" void kernel_launch(void* const* d_in, const int* in_sizes, int n_in,
                              void* d_out, int out_size, void* d_ws, size_t ws_size,
                              hipStream_t stream){
  const float* image = (const float*)d_in[0];
  const float* cb_w1 = (const float*)d_in[1];
  const float* cb_b1 = (const float*)d_in[2];
  const float* cb_w2 = (const float*)d_in[3];
  const float* cb_b2 = (const float*)d_in[4];
  const float* cb_ws = (const float*)d_in[5];
  const float* cb_bs = (const float*)d_in[6];
  const float* in_w  = (const float*)d_in[7];
  const float* dw_w  = (const float*)d_in[8];
  const float* dw_b  = (const float*)d_in[9];
  const float* xp_w  = (const float*)d_in[10];
  const float* dtp_w = (const float*)d_in[11];
  const float* dtp_b = (const float*)d_in[12];
  const float* A_logs= (const float*)d_in[13];
  const float* Ds    = (const float*)d_in[14];
  const float* ong   = (const float*)d_in[15];
  const float* onb   = (const float*)d_in[16];
  const float* op_w  = (const float*)d_in[17];
  const float* gn_g  = (const float*)d_in[18];
  const float* gn_b  = (const float*)d_in[19];
  const float* l1_w  = (const float*)d_in[20];
  const float* l1_b  = (const float*)d_in[21];
  const float* l2_w  = (const float*)d_in[22];
  const float* l2_b  = (const float*)d_in[23];
  const float* sh_w  = (const float*)d_in[24];
  const float* sh_b  = (const float*)d_in[25];

  const size_t SZ_X  = (size_t)BB*DMC*LL;        // 1,179,648
  const size_t SZ_C  = (size_t)BB*DIC*LL;        // 2,359,296
  const size_t SZ_XD = (size_t)BB*KD*20*LL;      // 1,310,720
  const size_t SZ_HP = (size_t)BB*KD*NCH*NS*DIC; // 4,718,592
  const size_t SZ_IP = (size_t)BB*CI*PP;         // img_pad
  const size_t SZ_TP = (size_t)BB*DMC*PP;        // tmp_pad (= xfin_pad)
  const size_t SZ_ZP = (size_t)BB*DIC*PP;        // xz_pad

  float* ws = (float*)d_ws;
  size_t off = 0;
  float* x     = ws + off; off += SZ_X;
  float* tmp   = ws + off; off += SZ_X;   // dense l1 out; later shrink pacc
  float* z_t   = ws + off; off += SZ_C;
  float* xi_t  = ws + off; off += SZ_C;
  float* xdbl  = ws + off; off += SZ_XD;
  float* cumA  = ws + off; off += SZ_HP;  // aliased: cumA (p1/p2) then y_t (p3..oproj)
  float* hp    = ws + off; off += SZ_HP;
  float* pads  = ws + off;
  float* img_pad = pads;
  float* tmp_pad = img_pad + SZ_IP;       // also xfin_pad for shrink
  float* xz_pad  = tmp_pad + SZ_TP;
  off += SZ_IP + SZ_TP + SZ_ZP;
  float* gnstats = ws + off; off += 2*BB*GRP;      // 96
  float* gnab    = ws + off; off += 2*BB*DMC;      // 576
  if (ws_size < off*sizeof(float)) return;
  float* y_t = cumA;

  dim3 blk(256);
  const int NPLANES = BB*CI + BB*DMC + BB*DIC;   // 888 padded planes

  k_halo<<<dim3(NPLANES), blk, 0, stream>>>(pads, NPLANES);
  k_pad_img<<<dim3(BB*CI*16), blk, 0, stream>>>(image, img_pad);
  k_conv1<<<dim3(BB*DMC*16), blk, 0, stream>>>(img_pad, cb_w1, cb_b1, tmp_pad);
  k_conv2init<<<dim3(BB*18*16), blk, 0, stream>>>(image, cb_b2, cb_ws, cb_bs, x);
  k_conv2<<<dim3(BB*2*18*16), blk, 0, stream>>>(tmp_pad, cb_w2, x);

  for (int i=0; i<NLAYER; ++i){
    const float* in_w_i  = in_w  + (size_t)i*2*DIC*DMC;
    const float* dw_w_i  = dw_w  + (size_t)i*DIC*9;
    const float* dw_b_i  = dw_b  + (size_t)i*DIC;
    const float* xp_w_i  = xp_w  + (size_t)i*KD*20*DIC;
    const float* dtp_w_i = dtp_w + (size_t)i*KD*DIC*RD;
    const float* dtp_b_i = dtp_b + (size_t)i*KD*DIC;
    const float* alog_i  = A_logs+ (size_t)i*KD*DIC*NS;
    const float* Ds_i    = Ds    + (size_t)i*KD*DIC;
    const float* ong_i   = ong   + (size_t)i*DIC;
    const float* onb_i   = onb   + (size_t)i*DIC;
    const float* op_w_i  = op_w  + (size_t)i*DMC*DIC;
    const float* gn_g_i  = gn_g  + (size_t)i*DMC;
    const float* gn_b_i  = gn_b  + (size_t)i*DMC;
    const float* l1_w_i  = l1_w  + (size_t)i*DMC*DMC;
    const float* l1_b_i  = l1_b  + (size_t)i*DMC;
    const float* l2_w_i  = l2_w  + (size_t)i*DMC*DMC;
    const float* l2_b_i  = l2_b  + (size_t)i*DMC;

    k_xz  <<<dim3(BB*36*16), blk, 0, stream>>>(x, in_w_i, xz_pad, z_t, (i==0)?1:0);
    k_dw  <<<dim3(BB*DIC*16), blk, 0, stream>>>(xz_pad, dw_w_i, dw_b_i, xi_t);
    k_xdbl<<<dim3(BB*4*KD*16), blk, 0, stream>>>(xi_t, xp_w_i, xdbl);
    k_p1  <<<dim3(BB*KD*NCH*DIC/256), blk, 0, stream>>>(xi_t, xdbl, dtp_w_i, dtp_b_i, alog_i, cumA, hp);
    k_p2  <<<dim3(BB*KD*NS*DIC/256), blk, 0, stream>>>(cumA, hp);
    k_p3  <<<dim3(BB*KD*NCH*DIC/256), blk, 0, stream>>>(xi_t, xdbl, dtp_w_i, dtp_b_i, alog_i, Ds_i, hp, y_t);
    k_oproj<<<dim3(BB*64), dim3(512), 0, stream>>>(y_t, z_t, ong_i, onb_i, op_w_i, x, gnstats);
    k_gnA <<<dim3(BB*GRP*16), blk, 0, stream>>>(x, gnstats);
    k_gnAB<<<dim3(2), blk, 0, stream>>>(gnstats, gn_g_i, gn_b_i, gnab);
    k_dense1<<<dim3(BB*18*16), blk, 0, stream>>>(x, gnab, l1_w_i, l1_b_i, tmp);
    k_dense2<<<dim3(BB*18*16), blk, 0, stream>>>(tmp, l2_w_i, l2_b_i, x,
                                                 (i==NLAYER-1) ? tmp_pad : (float*)nullptr);
  }

  // shrink: split-ic partials into tmp (reused as pacc), then bias+sigmoid
  hipMemsetAsync(tmp, 0, (size_t)BB*CI*LL*sizeof(float), stream);
  k_shrinkA<<<dim3(BB*24*16), blk, 0, stream>>>(tmp_pad, sh_w, tmp);
  k_sig<<<dim3((BB*CI*LL+255)/256), blk, 0, stream>>>(tmp, sh_b, (float*)d_out);
}